// Round 3
// baseline (224.991 us; speedup 1.0000x reference)
//
#include <hip/hip_runtime.h>

// Cascaded convex upsampling (SEAFLOW3DP): x16 -> x8 -> x4 -> x2 -> x1.
// One thread per PAIR of horizontally-adjacent coarse pixels -> 2x4x3 fine
// outputs. Mask loads are dwordx2 (pair shares the lane), tap loads are
// shared across the pair, stores are dwordx4.
//
// Mask layout (N,36,Hc,Wc), channel c = k*4 + sy*2 + sx, k = kh*3 + kw.
// Zero-padded taps contribute 0 to the numerator but keep their softmax
// weight in the denominator -> zero the TAP value, not the weight.

#define NB 4  // batch

template <int Hc, int Wc>
__global__ __launch_bounds__(256) void convex_up2(
    const float* __restrict__ flowIn,  // (NB,2,Hc,Wc)
    const float* __restrict__ dzIn,    // (NB,1,Hc,Wc)
    const float* __restrict__ mask,    // (NB,36,Hc,Wc)
    float* __restrict__ flowOut,       // ch0 at n*flowOutBS, ch1 at +H2*W2
    float* __restrict__ dzOut,         // at n*dzOutBS
    int flowOutBS, int dzOutBS)
{
    constexpr int HW = Hc * Wc;
    constexpr int W2 = Wc * 2;
    constexpr int WP = Wc / 2;  // coarse-pixel pairs per row

    int idx = blockIdx.x * 256 + threadIdx.x;  // grid sized exactly
    int wp = idx % WP;
    int t  = idx / WP;
    int hc = t % Hc;
    int n  = t / Hc;
    int wc0 = 2 * wp;  // left coarse pixel of the pair (A); right is wc0+1 (B)

    // ---- mask loads: 36 x dwordx2 (A in .x, B in .y) ----
    const float* mb = mask + (size_t)n * 36 * HW + (size_t)hc * Wc + wc0;
    float2 e2[36];
#pragma unroll
    for (int c = 0; c < 36; ++c) e2[c] = *(const float2*)(mb + (size_t)c * HW);

    // ---- tap loads: 3 rows x 4 cols (wc0-1 .. wc0+2) x 3 channels ----
    const float* fb = flowIn + (size_t)n * 2 * HW;
    const float* db = dzIn   + (size_t)n * HW;

    bool lv = (wp > 0);
    bool rv = (wp < WP - 1);
    int lc = lv ? wc0 - 1 : 0;        // clamped edge addresses (value zeroed)
    int rc = rv ? wc0 + 2 : Wc - 1;

    float tx[3][4], ty[3][4], tz[3][4];
#pragma unroll
    for (int kh = 0; kh < 3; ++kh) {
        int hh = hc + kh - 1;
        bool vh = (unsigned)hh < (unsigned)Hc;
        int hr = min(max(hh, 0), Hc - 1);
        const float* rx = fb + (size_t)hr * Wc;
        const float* ry = rx + HW;
        const float* rz = db + (size_t)hr * Wc;

        float2 cx = *(const float2*)(rx + wc0);
        float2 cy = *(const float2*)(ry + wc0);
        float2 cz = *(const float2*)(rz + wc0);
        float lx = rx[lc], ly = ry[lc], lz = rz[lc];
        float rxe = rx[rc], rye = ry[rc], rze = rz[rc];

        bool vl = vh && lv, vr = vh && rv;
        tx[kh][0] = vl ? lx : 0.f;  tx[kh][1] = vh ? cx.x : 0.f;
        tx[kh][2] = vh ? cx.y : 0.f; tx[kh][3] = vr ? rxe : 0.f;
        ty[kh][0] = vl ? ly : 0.f;  ty[kh][1] = vh ? cy.x : 0.f;
        ty[kh][2] = vh ? cy.y : 0.f; ty[kh][3] = vr ? rye : 0.f;
        tz[kh][0] = vl ? lz : 0.f;  tz[kh][1] = vh ? cz.x : 0.f;
        tz[kh][2] = vh ? cz.y : 0.f; tz[kh][3] = vr ? rze : 0.f;
    }

    // ---- softmax exps (no max-sub: fp32 + N(0,1)-scale inputs, safe) ----
#pragma unroll
    for (int c = 0; c < 36; ++c) {
        e2[c].x = __expf(e2[c].x);
        e2[c].y = __expf(e2[c].y);
    }

    // ---- accumulate 4 quadrants x 2 pixels ----
    float sA[4] = {0, 0, 0, 0}, axA[4] = {0, 0, 0, 0},
          ayA[4] = {0, 0, 0, 0}, azA[4] = {0, 0, 0, 0};
    float sB[4] = {0, 0, 0, 0}, axB[4] = {0, 0, 0, 0},
          ayB[4] = {0, 0, 0, 0}, azB[4] = {0, 0, 0, 0};
#pragma unroll
    for (int k = 0; k < 9; ++k) {
        int kh = k / 3, kw = k % 3;
#pragma unroll
        for (int q = 0; q < 4; ++q) {
            float eA = e2[k * 4 + q].x, eB = e2[k * 4 + q].y;
            sA[q]  += eA;               sB[q]  += eB;
            axA[q] += eA * tx[kh][kw];  axB[q] += eB * tx[kh][kw + 1];
            ayA[q] += eA * ty[kh][kw];  ayB[q] += eB * ty[kh][kw + 1];
            azA[q] += eA * tz[kh][kw];  azB[q] += eB * tz[kh][kw + 1];
        }
    }

    // ---- normalize + dwordx4 stores (fine cols 4wp..4wp+3) ----
    float* fo0 = flowOut + (size_t)n * flowOutBS;
    float* fo1 = fo0 + (size_t)(2 * Hc) * W2;
    float* dzo = dzOut + (size_t)n * dzOutBS;

#pragma unroll
    for (int sy = 0; sy < 2; ++sy) {
        int qa = sy * 2, qb = qa + 1;
        float iA0 = __builtin_amdgcn_rcpf(sA[qa]);
        float iA1 = __builtin_amdgcn_rcpf(sA[qb]);
        float iB0 = __builtin_amdgcn_rcpf(sB[qa]);
        float iB1 = __builtin_amdgcn_rcpf(sB[qb]);
        size_t ro = (size_t)(2 * hc + sy) * W2 + 4 * wp;
        float4 vx = {2.f * axA[qa] * iA0, 2.f * axA[qb] * iA1,
                     2.f * axB[qa] * iB0, 2.f * axB[qb] * iB1};
        float4 vy = {2.f * ayA[qa] * iA0, 2.f * ayA[qb] * iA1,
                     2.f * ayB[qa] * iB0, 2.f * ayB[qb] * iB1};
        float4 vz = {azA[qa] * iA0, azA[qb] * iA1,
                     azB[qa] * iB0, azB[qb] * iB1};
        *(float4*)(fo0 + ro) = vx;
        *(float4*)(fo1 + ro) = vy;
        *(float4*)(dzo + ro) = vz;
    }
}

extern "C" void kernel_launch(void* const* d_in, const int* in_sizes, int n_in,
                              void* d_out, int out_size, void* d_ws, size_t ws_size,
                              hipStream_t stream) {
    const float* flow16 = (const float*)d_in[0];  // (4,2,48,64)
    const float* dz16   = (const float*)d_in[1];  // (4,1,48,64)
    const float* mask16 = (const float*)d_in[2];  // (4,36,48,64)
    const float* mask8  = (const float*)d_in[3];  // (4,36,96,128)
    const float* mask4  = (const float*)d_in[4];  // (4,36,192,256)
    const float* mask2  = (const float*)d_in[5];  // (4,36,384,512)

    float* ws = (float*)d_ws;
    float* flowA = ws;                               // 4*2*96*128
    float* dzA   = flowA + 4 * 2 * 96 * 128;         // 4*1*96*128
    float* flowB = dzA   + 4 * 96 * 128;             // 4*2*192*256
    float* dzB   = flowB + 4 * 2 * 192 * 256;        // 4*1*192*256
    float* flowC = dzB   + 4 * 192 * 256;            // 4*2*384*512
    float* dzC   = flowC + 4 * 2 * 384 * 512;        // 4*1*384*512

    float* out = (float*)d_out;                      // (4,3,768,1024)
    const int HW1 = 768 * 1024;

    // threads per stage = NB*Hc*Wc/2 (all multiples of 256)
    hipLaunchKernelGGL((convex_up2<48, 64>), dim3(NB * 48 * 64 / 2 / 256), dim3(256), 0, stream,
                       flow16, dz16, mask16, flowA, dzA, 2 * 96 * 128, 96 * 128);
    hipLaunchKernelGGL((convex_up2<96, 128>), dim3(NB * 96 * 128 / 2 / 256), dim3(256), 0, stream,
                       flowA, dzA, mask8, flowB, dzB, 2 * 192 * 256, 192 * 256);
    hipLaunchKernelGGL((convex_up2<192, 256>), dim3(NB * 192 * 256 / 2 / 256), dim3(256), 0, stream,
                       flowB, dzB, mask4, flowC, dzC, 2 * 384 * 512, 384 * 512);
    hipLaunchKernelGGL((convex_up2<384, 512>), dim3(NB * 384 * 512 / 2 / 256), dim3(256), 0, stream,
                       flowC, dzC, mask2, out, out + 2 * HW1, 3 * HW1, 3 * HW1);
}